// Round 1
// baseline (752.015 us; speedup 1.0000x reference)
//
#include <hip/hip_runtime.h>
#include <hip/hip_bf16.h>

// Problem constants
#define BROWS 8192      // B*N = 8*1024
#define DDIM 3
#define CDIM 64
#define KF 8192         // F = 2*C*C
#define NINV 512
#define NEQ 1024        // per head
#define NTOT 2560       // 512 + 1024 + 1024
#define BAS 16
#define UEQ 64

typedef float f32x4 __attribute__((ext_vector_type(4)));
typedef __bf16 bf16x8_t __attribute__((ext_vector_type(8)));

__device__ __forceinline__ void async_copy16(const void* g, void* l) {
    __builtin_amdgcn_global_load_lds(
        (__attribute__((address_space(1))) void*)(g),
        (__attribute__((address_space(3))) void*)(l), 16, 0, 0);
}

// ---------------------------------------------------------------------------
// Kernel 1: per-row l2norm + Gram blocks -> feats bf16 [8192][8192]
// ---------------------------------------------------------------------------
__global__ __launch_bounds__(256) void feats_kernel(
    const float* __restrict__ t1, const float* __restrict__ t2,
    const float* __restrict__ u1, const float* __restrict__ u2,
    __hip_bfloat16* __restrict__ feats)
{
    const int row = blockIdx.x;
    const int tid = threadIdx.x;
    __shared__ float sT[2 * DDIM * CDIM];   // [head][d][c]
    __shared__ float sU[2 * DDIM * CDIM];   // scaled u

    const size_t base = (size_t)row * (DDIM * CDIM);
    if (tid < 192) {
        sT[tid]       = t1[base + tid];
        sT[192 + tid] = t2[base + tid];
        sU[tid]       = u1[base + tid];
        sU[192 + tid] = u2[base + tid];
    }
    __syncthreads();
    if (tid < 128) {
        const int h = tid >> 6, c = tid & 63;
        float* U = sU + h * 192;
        float sq = U[c] * U[c] + U[64 + c] * U[64 + c] + U[128 + c] * U[128 + c];
        float s = 1.0f / sqrtf(fmaxf(sq, 0.01f));
        U[c] *= s; U[64 + c] *= s; U[128 + c] *= s;
    }
    __syncthreads();
    __hip_bfloat16* frow = feats + (size_t)row * KF;
    #pragma unroll
    for (int kk = 0; kk < KF; kk += 256) {
        const int k = kk + tid;
        const int h = k >> 12, r = k & 4095, i = r >> 6, j = r & 63;
        const float* T = sT + h * 192;
        const float* U = sU + h * 192;
        float v = T[i] * U[j] + T[64 + i] * U[64 + j] + T[128 + i] * U[128 + j];
        frow[k] = __float2bfloat16(v);
    }
}

// ---------------------------------------------------------------------------
// Kernel 2: transpose+convert W (K x N fp32, three sources) -> WT bf16 [NTOT][KF]
// ---------------------------------------------------------------------------
__global__ __launch_bounds__(256) void wt_kernel(
    const float* __restrict__ W_inv, const float* __restrict__ W_eq,
    __hip_bfloat16* __restrict__ WT)
{
    __shared__ float tile[32][33];
    const int tx = threadIdx.x;       // 0..31
    const int ty = threadIdx.y;       // 0..7
    const int n0 = blockIdx.x * 32;   // output column block (0..2559)
    const int k0 = blockIdx.y * 32;   // K block (0..8191)

    const float* src; int ldn, nl0;
    if (n0 < NINV)            { src = W_inv;                       ldn = NINV; nl0 = n0; }
    else if (n0 < NINV + NEQ) { src = W_eq;                        ldn = NEQ;  nl0 = n0 - NINV; }
    else                      { src = W_eq + (size_t)KF * NEQ;     ldn = NEQ;  nl0 = n0 - NINV - NEQ; }

    #pragma unroll
    for (int i = 0; i < 4; ++i) {
        int kl = ty + i * 8;
        tile[kl][tx] = src[(size_t)(k0 + kl) * ldn + nl0 + tx];
    }
    __syncthreads();
    #pragma unroll
    for (int i = 0; i < 4; ++i) {
        int nl = ty + i * 8;
        WT[(size_t)(n0 + nl) * KF + k0 + tx] = __float2bfloat16(tile[tx][nl]);
    }
}

// ---------------------------------------------------------------------------
// Kernel 3: concat BN params into [NTOT] arrays
// ---------------------------------------------------------------------------
__global__ __launch_bounds__(256) void params_kernel(
    const float* __restrict__ b_inv, const float* __restrict__ g_inv, const float* __restrict__ be_inv,
    const float* __restrict__ b_eq,  const float* __restrict__ g_eq,  const float* __restrict__ be_eq,
    float* __restrict__ cb, float* __restrict__ cg, float* __restrict__ cbe)
{
    int n = blockIdx.x * 256 + threadIdx.x;
    if (n >= NTOT) return;
    float b, g, be;
    if (n < NINV) { b = b_inv[n]; g = g_inv[n]; be = be_inv[n]; }
    else {
        int h = (n - NINV) / NEQ, nl = (n - NINV) % NEQ;
        b = b_eq[h * NEQ + nl]; g = g_eq[h * NEQ + nl]; be = be_eq[h * NEQ + nl];
    }
    cb[n] = b; cg[n] = g; cbe[n] = be;
}

// ---------------------------------------------------------------------------
// Kernel 4: bf16 MFMA GEMM (m97 structure): A[8192][8192] x WT[2560][8192]^T
//           epilogue: BN + ReLU; n<512 -> d_out, else -> Yeq ws
// ---------------------------------------------------------------------------
#define BM 128
#define BN 128
#define BK 32

__global__ __launch_bounds__(256) void gemm_kernel(
    const __hip_bfloat16* __restrict__ A,   // [BROWS][KF]
    const __hip_bfloat16* __restrict__ BT,  // [NTOT][KF]
    const float* __restrict__ cb, const float* __restrict__ cg, const float* __restrict__ cbe,
    float* __restrict__ out_inv,            // d_out: [BROWS][NINV]
    float* __restrict__ Yeq)                // ws:    [BROWS][2048]
{
    __shared__ alignas(16) __hip_bfloat16 As[BM * BK];  // 8 KB
    __shared__ alignas(16) __hip_bfloat16 Bs[BN * BK];  // 8 KB

    const int tid  = threadIdx.x;
    const int wave = tid >> 6;
    const int lane = tid & 63;
    const int m0 = blockIdx.y * BM;
    const int n0 = blockIdx.x * BN;
    const int wm = (wave & 1) * 64;
    const int wn = (wave >> 1) * 64;

    f32x4 acc[4][4] = {};

    const int rpart = lane & 3;          // 16B segment within a 64B row
    const int rsub  = lane >> 2;         // row within a 16-row group

    for (int kt = 0; kt < KF; kt += BK) {
        __syncthreads();
        #pragma unroll
        for (int c = 0; c < 2; ++c) {
            const int rowA = wave * 32 + c * 16 + rsub;
            async_copy16(A  + (size_t)(m0 + rowA) * KF + kt + rpart * 8,
                         (char*)As + wave * 2048 + c * 1024 + lane * 16);
            const int rowB = wave * 32 + c * 16 + rsub;
            async_copy16(BT + (size_t)(n0 + rowB) * KF + kt + rpart * 8,
                         (char*)Bs + wave * 2048 + c * 1024 + lane * 16);
        }
        __syncthreads();

        bf16x8_t a[4], b[4];
        #pragma unroll
        for (int mt = 0; mt < 4; ++mt)
            a[mt] = *reinterpret_cast<const bf16x8_t*>(
                &As[(wm + mt * 16 + (lane & 15)) * BK + ((lane >> 4) << 3)]);
        #pragma unroll
        for (int nt = 0; nt < 4; ++nt)
            b[nt] = *reinterpret_cast<const bf16x8_t*>(
                &Bs[(wn + nt * 16 + (lane & 15)) * BK + ((lane >> 4) << 3)]);

        #pragma unroll
        for (int mt = 0; mt < 4; ++mt)
            #pragma unroll
            for (int nt = 0; nt < 4; ++nt)
                acc[mt][nt] = __builtin_amdgcn_mfma_f32_16x16x32_bf16(
                    a[mt], b[nt], acc[mt][nt], 0, 0, 0);
    }

    // epilogue: y = relu(g * (acc + b) / sqrt(1.001) + be)
    const float RSQ = 0.9995003746877732f;
    #pragma unroll
    for (int nt = 0; nt < 4; ++nt) {
        const int gn = n0 + wn + nt * 16 + (lane & 15);
        const float bb = cb[gn];
        const float gg = cg[gn] * RSQ;
        const float be = cbe[gn];
        #pragma unroll
        for (int mt = 0; mt < 4; ++mt) {
            const int gmb = m0 + wm + mt * 16 + ((lane >> 4) << 2);
            #pragma unroll
            for (int r = 0; r < 4; ++r) {
                float y = fmaxf(gg * (acc[mt][nt][r] + bb) + be, 0.0f);
                const size_t gm = gmb + r;
                if (n0 < NINV) out_inv[gm * NINV + gn] = y;
                else           Yeq[gm * 2048 + (gn - NINV)] = y;
            }
        }
    }
}

// ---------------------------------------------------------------------------
// Kernel 5: basis recombine: eq[b,n,m,l*64+i] = sum_j wl[row, l*1024+i*16+j] * Vl[row,m,j]
// ---------------------------------------------------------------------------
__global__ __launch_bounds__(128) void eqcomb_kernel(
    const float* __restrict__ Yeq,   // [BROWS][2048]
    const float* __restrict__ V1, const float* __restrict__ V2,
    float* __restrict__ out_eq)      // [BROWS][3][128]
{
    const int row = blockIdx.x;
    const int tid = threadIdx.x;     // 128
    __shared__ float sV[2][DDIM][BAS];
    if (tid < 96) {
        const int h = tid / 48, rem = tid % 48;
        const float* V = h ? V2 : V1;
        sV[h][rem / BAS][rem % BAS] = V[(size_t)row * (DDIM * BAS) + rem];
    }
    __syncthreads();
    const int l = tid >> 6, u = tid & 63;
    const float4* y4 = reinterpret_cast<const float4*>(
        Yeq + (size_t)row * 2048 + l * 1024 + u * BAS);
    float a0 = 0.f, a1 = 0.f, a2 = 0.f;
    #pragma unroll
    for (int q = 0; q < 4; ++q) {
        float4 w = y4[q];
        const float* v0 = sV[l][0] + q * 4;
        const float* v1 = sV[l][1] + q * 4;
        const float* v2 = sV[l][2] + q * 4;
        a0 += w.x * v0[0] + w.y * v0[1] + w.z * v0[2] + w.w * v0[3];
        a1 += w.x * v1[0] + w.y * v1[1] + w.z * v1[2] + w.w * v1[3];
        a2 += w.x * v2[0] + w.y * v2[1] + w.z * v2[2] + w.w * v2[3];
    }
    float* o = out_eq + (size_t)row * (DDIM * 128);
    o[0 * 128 + l * 64 + u] = a0;
    o[1 * 128 + l * 64 + u] = a1;
    o[2 * 128 + l * 64 + u] = a2;
}

// ---------------------------------------------------------------------------
extern "C" void kernel_launch(void* const* d_in, const int* in_sizes, int n_in,
                              void* d_out, int out_size, void* d_ws, size_t ws_size,
                              hipStream_t stream) {
    const float* t1    = (const float*)d_in[0];
    const float* t2    = (const float*)d_in[1];
    const float* u1    = (const float*)d_in[2];
    const float* u2    = (const float*)d_in[3];
    const float* V1    = (const float*)d_in[4];
    const float* V2    = (const float*)d_in[5];
    const float* W_inv = (const float*)d_in[6];
    const float* b_inv = (const float*)d_in[7];
    const float* g_inv = (const float*)d_in[8];
    const float* be_inv= (const float*)d_in[9];
    const float* W_eq  = (const float*)d_in[10];
    const float* b_eq  = (const float*)d_in[11];
    const float* g_eq  = (const float*)d_in[12];
    const float* be_eq = (const float*)d_in[13];
    float* out = (float*)d_out;

    // workspace layout (bytes)
    char* ws = (char*)d_ws;
    __hip_bfloat16* feats = (__hip_bfloat16*)(ws);                       // 134,217,728
    __hip_bfloat16* WT    = (__hip_bfloat16*)(ws + 134217728);           //  41,943,040
    float*          Yeq   = (float*)(ws + 176160768);                    //  67,108,864
    float*          cb    = (float*)(ws + 243269632);
    float*          cg    = (float*)(ws + 243279872);
    float*          cbe   = (float*)(ws + 243290112);

    float* out_inv = out;                                  // [8192][512]
    float* out_eq  = out + (size_t)BROWS * NINV;           // [8192][3][128]

    hipLaunchKernelGGL(feats_kernel, dim3(BROWS), dim3(256), 0, stream,
                       t1, t2, u1, u2, feats);
    hipLaunchKernelGGL(wt_kernel, dim3(NTOT / 32, KF / 32), dim3(32, 8), 0, stream,
                       W_inv, W_eq, WT);
    hipLaunchKernelGGL(params_kernel, dim3((NTOT + 255) / 256), dim3(256), 0, stream,
                       b_inv, g_inv, be_inv, b_eq, g_eq, be_eq, cb, cg, cbe);
    hipLaunchKernelGGL(gemm_kernel, dim3(NTOT / BN, BROWS / BM), dim3(256), 0, stream,
                       feats, WT, cb, cg, cbe, out_inv, Yeq);
    hipLaunchKernelGGL(eqcomb_kernel, dim3(BROWS), dim3(128), 0, stream,
                       Yeq, V1, V2, out_eq);
}

// Round 2
// 747.838 us; speedup vs baseline: 1.0056x; 1.0056x over previous
//
#include <hip/hip_runtime.h>
#include <hip/hip_bf16.h>

// Problem constants
#define BROWS 8192      // B*N = 8*1024
#define DDIM 3
#define CDIM 64
#define KF 8192         // F = 2*C*C
#define NINV 512
#define NEQ 1024        // per head
#define NTOT 2560       // 512 + 1024 + 1024
#define BAS 16
#define UEQ 64

typedef float f32x4 __attribute__((ext_vector_type(4)));
typedef __bf16 bf16x8_t __attribute__((ext_vector_type(8)));
typedef __bf16 bf16x4_t __attribute__((ext_vector_type(4)));

__device__ __forceinline__ void async_copy16(const void* g, void* l) {
    __builtin_amdgcn_global_load_lds(
        (__attribute__((address_space(1))) void*)(g),
        (__attribute__((address_space(3))) void*)(l), 16, 0, 0);
}

// ---------------------------------------------------------------------------
// Kernel 1: per-row l2norm + Gram blocks -> feats bf16 [8192][8192]
// ---------------------------------------------------------------------------
__global__ __launch_bounds__(256) void feats_kernel(
    const float* __restrict__ t1, const float* __restrict__ t2,
    const float* __restrict__ u1, const float* __restrict__ u2,
    __hip_bfloat16* __restrict__ feats)
{
    const int row = blockIdx.x;
    const int tid = threadIdx.x;
    __shared__ float sT[2 * DDIM * CDIM];   // [head][d][c]
    __shared__ float sU[2 * DDIM * CDIM];   // scaled u

    const size_t base = (size_t)row * (DDIM * CDIM);
    if (tid < 192) {
        sT[tid]       = t1[base + tid];
        sT[192 + tid] = t2[base + tid];
        sU[tid]       = u1[base + tid];
        sU[192 + tid] = u2[base + tid];
    }
    __syncthreads();
    if (tid < 128) {
        const int h = tid >> 6, c = tid & 63;
        float* U = sU + h * 192;
        float sq = U[c] * U[c] + U[64 + c] * U[64 + c] + U[128 + c] * U[128 + c];
        float s = 1.0f / sqrtf(fmaxf(sq, 0.01f));
        U[c] *= s; U[64 + c] *= s; U[128 + c] *= s;
    }
    __syncthreads();
    __hip_bfloat16* frow = feats + (size_t)row * KF;
    #pragma unroll
    for (int kk = 0; kk < KF; kk += 1024) {
        const int k = kk + tid * 4;
        const int h = k >> 12, r = k & 4095, i = r >> 6, j = r & 63;
        const float* T = sT + h * 192;
        const float* U = sU + h * 192;
        const float ti0 = T[i], ti1 = T[64 + i], ti2 = T[128 + i];
        bf16x4_t v;
        #pragma unroll
        for (int q = 0; q < 4; ++q) {
            float val = ti0 * U[j + q] + ti1 * U[64 + j + q] + ti2 * U[128 + j + q];
            v[q] = (__bf16)val;
        }
        *reinterpret_cast<bf16x4_t*>(frow + k) = v;
    }
}

// ---------------------------------------------------------------------------
// Kernel 2: transpose+convert W (K x N fp32, three sources) -> WT bf16 [NTOT][KF]
// ---------------------------------------------------------------------------
__global__ __launch_bounds__(256) void wt_kernel(
    const float* __restrict__ W_inv, const float* __restrict__ W_eq,
    __hip_bfloat16* __restrict__ WT)
{
    __shared__ float tile[32][33];
    const int tid = threadIdx.x;
    const int tx = tid & 31;          // n within tile (load)
    const int ty = tid >> 5;          // 0..7
    const int n0 = blockIdx.x * 32;   // output column block (0..2559)
    const int k0 = blockIdx.y * 32;   // K block (0..8191)

    const float* src; int ldn, nl0;
    if (n0 < NINV)            { src = W_inv;                       ldn = NINV; nl0 = n0; }
    else if (n0 < NINV + NEQ) { src = W_eq;                        ldn = NEQ;  nl0 = n0 - NINV; }
    else                      { src = W_eq + (size_t)KF * NEQ;     ldn = NEQ;  nl0 = n0 - NINV - NEQ; }

    #pragma unroll
    for (int i = 0; i < 4; ++i) {
        int kl = ty + i * 8;
        tile[kl][tx] = src[(size_t)(k0 + kl) * ldn + nl0 + tx];
    }
    __syncthreads();
    // store phase: each thread packs 4 consecutive k for one n (8 B store)
    const int n_l = tid >> 3;
    const int k4  = (tid & 7) * 4;
    bf16x4_t v;
    #pragma unroll
    for (int q = 0; q < 4; ++q) v[q] = (__bf16)tile[k4 + q][n_l];
    *reinterpret_cast<bf16x4_t*>(&WT[(size_t)(n0 + n_l) * KF + k0 + k4]) = v;
}

// ---------------------------------------------------------------------------
// Kernel 3: concat BN params into [NTOT] arrays
// ---------------------------------------------------------------------------
__global__ __launch_bounds__(256) void params_kernel(
    const float* __restrict__ b_inv, const float* __restrict__ g_inv, const float* __restrict__ be_inv,
    const float* __restrict__ b_eq,  const float* __restrict__ g_eq,  const float* __restrict__ be_eq,
    float* __restrict__ cb, float* __restrict__ cg, float* __restrict__ cbe)
{
    int n = blockIdx.x * 256 + threadIdx.x;
    if (n >= NTOT) return;
    float b, g, be;
    if (n < NINV) { b = b_inv[n]; g = g_inv[n]; be = be_inv[n]; }
    else {
        int h = (n - NINV) / NEQ, nl = (n - NINV) % NEQ;
        b = b_eq[h * NEQ + nl]; g = g_eq[h * NEQ + nl]; be = be_eq[h * NEQ + nl];
    }
    cb[n] = b; cg[n] = g; cbe[n] = be;
}

// ---------------------------------------------------------------------------
// Kernel 4: bf16 MFMA GEMM, double-buffered LDS + chunk swizzle + XCD swizzle
// ---------------------------------------------------------------------------
#define BM 128
#define BN 128
#define BK 32

__global__ __launch_bounds__(256) void gemm_kernel(
    const __hip_bfloat16* __restrict__ A,   // [BROWS][KF]
    const __hip_bfloat16* __restrict__ BT,  // [NTOT][KF]
    const float* __restrict__ cb, const float* __restrict__ cg, const float* __restrict__ cbe,
    float* __restrict__ out_inv,            // d_out: [BROWS][NINV]
    float* __restrict__ Yeq)                // ws:    [BROWS][2048]
{
    __shared__ alignas(16) __hip_bfloat16 As[2][BM * BK];  // 2 x 8 KB
    __shared__ alignas(16) __hip_bfloat16 Bs[2][BN * BK];  // 2 x 8 KB

    const int tid  = threadIdx.x;
    const int wave = tid >> 6;
    const int lane = tid & 63;

    // XCD-aware decode: 1280 blocks; xcd = b%8 owns m-stripes xcd*8..+7,
    // n iterates fastest within the XCD's slots -> A-stripe reuse in per-XCD L2.
    const int b    = blockIdx.x;
    const int xcd  = b & 7;
    const int slot = b >> 3;            // 0..159
    const int n0   = (slot % 20) * BN;
    const int m0   = (xcd * 8 + slot / 20) * BM;

    const int wm = (wave & 1) * 64;
    const int wn = (wave >> 1) * 64;

    f32x4 acc[4][4] = {};

    const int rpart = lane & 3;          // logical 16B chunk slot within 64B row
    const int rsub  = lane >> 2;         // row within a 16-row group

    // staging: lane L serves (rowLocal, phys chunk rpart); global source uses
    // the swizzled logical chunk: log = (rpart - (rowLocal>>1)) & 3
    const int rowL0 = wave * 32 + rsub;
    const int rowL1 = rowL0 + 16;
    const int ck0 = ((rpart - (rowL0 >> 1)) & 3) * 8;   // elements
    const int ck1 = ((rpart - (rowL1 >> 1)) & 3) * 8;
    const __hip_bfloat16* gA0 = A  + (size_t)(m0 + rowL0) * KF + ck0;
    const __hip_bfloat16* gA1 = A  + (size_t)(m0 + rowL1) * KF + ck1;
    const __hip_bfloat16* gB0 = BT + (size_t)(n0 + rowL0) * KF + ck0;
    const __hip_bfloat16* gB1 = BT + (size_t)(n0 + rowL1) * KF + ck1;

    // ds_read side: phys chunk = (log chunk + (row>>1)) & 3 ; independent of mt/nt
    const int arow  = wm + (lane & 15);
    const int brow  = wn + (lane & 15);
    const int achnk = (((lane >> 4) + (arow >> 1)) & 3) * 8;
    const int bchnk = (((lane >> 4) + (brow >> 1)) & 3) * 8;

    // prologue: tile 0 -> buffer 0
    {
        char* dA = (char*)&As[0][0] + wave * 2048 + lane * 16;
        char* dB = (char*)&Bs[0][0] + wave * 2048 + lane * 16;
        async_copy16(gA0, dA);
        async_copy16(gA1, dA + 1024);
        async_copy16(gB0, dB);
        async_copy16(gB1, dB + 1024);
    }

    const int ITERS = KF / BK;   // 256
    for (int i = 0; i < ITERS; ++i) {
        const int cur = i & 1;
        if (i + 1 < ITERS) {
            const size_t ko = (size_t)(i + 1) * BK;
            char* dA = (char*)&As[cur ^ 1][0] + wave * 2048 + lane * 16;
            char* dB = (char*)&Bs[cur ^ 1][0] + wave * 2048 + lane * 16;
            async_copy16(gA0 + ko, dA);
            async_copy16(gA1 + ko, dA + 1024);
            async_copy16(gB0 + ko, dB);
            async_copy16(gB1 + ko, dB + 1024);
            // wait only for the 4 oldest (current tile); 4 just-issued stay in flight
            asm volatile("s_waitcnt vmcnt(4)" ::: "memory");
        } else {
            asm volatile("s_waitcnt vmcnt(0)" ::: "memory");
        }
        asm volatile("" ::: "memory");
        __builtin_amdgcn_s_barrier();
        asm volatile("" ::: "memory");

        bf16x8_t a[4], bb[4];
        #pragma unroll
        for (int mt = 0; mt < 4; ++mt)
            a[mt] = *reinterpret_cast<const bf16x8_t*>(
                &As[cur][(wm + mt * 16 + (lane & 15)) * BK + achnk]);
        #pragma unroll
        for (int nt = 0; nt < 4; ++nt)
            bb[nt] = *reinterpret_cast<const bf16x8_t*>(
                &Bs[cur][(wn + nt * 16 + (lane & 15)) * BK + bchnk]);

        #pragma unroll
        for (int mt = 0; mt < 4; ++mt)
            #pragma unroll
            for (int nt = 0; nt < 4; ++nt)
                acc[mt][nt] = __builtin_amdgcn_mfma_f32_16x16x32_bf16(
                    a[mt], bb[nt], acc[mt][nt], 0, 0, 0);

        asm volatile("" ::: "memory");
        __builtin_amdgcn_s_barrier();
        asm volatile("" ::: "memory");
    }

    // epilogue: y = relu(g * (acc + b) / sqrt(1.001) + be)
    const float RSQ = 0.9995003746877732f;
    #pragma unroll
    for (int nt = 0; nt < 4; ++nt) {
        const int gn = n0 + wn + nt * 16 + (lane & 15);
        const float bbp = cb[gn];
        const float gg  = cg[gn] * RSQ;
        const float bep = cbe[gn];
        #pragma unroll
        for (int mt = 0; mt < 4; ++mt) {
            const int gmb = m0 + wm + mt * 16 + ((lane >> 4) << 2);
            #pragma unroll
            for (int r = 0; r < 4; ++r) {
                float y = fmaxf(gg * (acc[mt][nt][r] + bbp) + bep, 0.0f);
                const size_t gm = gmb + r;
                if (n0 < NINV) out_inv[gm * NINV + gn] = y;
                else           Yeq[gm * 2048 + (gn - NINV)] = y;
            }
        }
    }
}

// ---------------------------------------------------------------------------
// Kernel 5: basis recombine
// ---------------------------------------------------------------------------
__global__ __launch_bounds__(128) void eqcomb_kernel(
    const float* __restrict__ Yeq,   // [BROWS][2048]
    const float* __restrict__ V1, const float* __restrict__ V2,
    float* __restrict__ out_eq)      // [BROWS][3][128]
{
    const int row = blockIdx.x;
    const int tid = threadIdx.x;     // 128
    __shared__ float sV[2][DDIM][BAS];
    if (tid < 96) {
        const int h = tid / 48, rem = tid % 48;
        const float* V = h ? V2 : V1;
        sV[h][rem / BAS][rem % BAS] = V[(size_t)row * (DDIM * BAS) + rem];
    }
    __syncthreads();
    const int l = tid >> 6, u = tid & 63;
    const float4* y4 = reinterpret_cast<const float4*>(
        Yeq + (size_t)row * 2048 + l * 1024 + u * BAS);
    float a0 = 0.f, a1 = 0.f, a2 = 0.f;
    #pragma unroll
    for (int q = 0; q < 4; ++q) {
        float4 w = y4[q];
        const float* v0 = sV[l][0] + q * 4;
        const float* v1 = sV[l][1] + q * 4;
        const float* v2 = sV[l][2] + q * 4;
        a0 += w.x * v0[0] + w.y * v0[1] + w.z * v0[2] + w.w * v0[3];
        a1 += w.x * v1[0] + w.y * v1[1] + w.z * v1[2] + w.w * v1[3];
        a2 += w.x * v2[0] + w.y * v2[1] + w.z * v2[2] + w.w * v2[3];
    }
    float* o = out_eq + (size_t)row * (DDIM * 128);
    o[0 * 128 + l * 64 + u] = a0;
    o[1 * 128 + l * 64 + u] = a1;
    o[2 * 128 + l * 64 + u] = a2;
}

// ---------------------------------------------------------------------------
extern "C" void kernel_launch(void* const* d_in, const int* in_sizes, int n_in,
                              void* d_out, int out_size, void* d_ws, size_t ws_size,
                              hipStream_t stream) {
    const float* t1    = (const float*)d_in[0];
    const float* t2    = (const float*)d_in[1];
    const float* u1    = (const float*)d_in[2];
    const float* u2    = (const float*)d_in[3];
    const float* V1    = (const float*)d_in[4];
    const float* V2    = (const float*)d_in[5];
    const float* W_inv = (const float*)d_in[6];
    const float* b_inv = (const float*)d_in[7];
    const float* g_inv = (const float*)d_in[8];
    const float* be_inv= (const float*)d_in[9];
    const float* W_eq  = (const float*)d_in[10];
    const float* b_eq  = (const float*)d_in[11];
    const float* g_eq  = (const float*)d_in[12];
    const float* be_eq = (const float*)d_in[13];
    float* out = (float*)d_out;

    // workspace layout (bytes)
    char* ws = (char*)d_ws;
    __hip_bfloat16* feats = (__hip_bfloat16*)(ws);                       // 134,217,728
    __hip_bfloat16* WT    = (__hip_bfloat16*)(ws + 134217728);           //  41,943,040
    float*          Yeq   = (float*)(ws + 176160768);                    //  67,108,864
    float*          cb    = (float*)(ws + 243269632);
    float*          cg    = (float*)(ws + 243279872);
    float*          cbe   = (float*)(ws + 243290112);

    float* out_inv = out;                                  // [8192][512]
    float* out_eq  = out + (size_t)BROWS * NINV;           // [8192][3][128]

    hipLaunchKernelGGL(feats_kernel, dim3(BROWS), dim3(256), 0, stream,
                       t1, t2, u1, u2, feats);
    hipLaunchKernelGGL(wt_kernel, dim3(NTOT / 32, KF / 32), dim3(256), 0, stream,
                       W_inv, W_eq, WT);
    hipLaunchKernelGGL(params_kernel, dim3((NTOT + 255) / 256), dim3(256), 0, stream,
                       b_inv, g_inv, be_inv, b_eq, g_eq, be_eq, cb, cg, cbe);
    hipLaunchKernelGGL(gemm_kernel, dim3((NTOT / BN) * (BROWS / BM)), dim3(256), 0, stream,
                       feats, WT, cb, cg, cbe, out_inv, Yeq);
    hipLaunchKernelGGL(eqcomb_kernel, dim3(BROWS), dim3(128), 0, stream,
                       Yeq, V1, V2, out_eq);
}